// Round 15
// baseline (168.466 us; speedup 1.0000x reference)
//
#include <hip/hip_runtime.h>
#include <math.h>

#define D_EMB 768
#define SEQN 2048
#define NB 4
#define NH 12
#define HDIM 64
#define MTOT (NB*SEQN)   // 8192
#define SCLQ 0.18033688011112042f   // 0.125 * log2(e)

typedef unsigned int u32;
typedef unsigned short u16;
typedef short sh4 __attribute__((ext_vector_type(4)));
typedef short bf16x8 __attribute__((ext_vector_type(8)));
typedef float f32x16 __attribute__((ext_vector_type(16)));

#define MFMA32(a,b,c) __builtin_amdgcn_mfma_f32_32x32x16_bf16((a),(b),(c),0,0,0)

__device__ __forceinline__ u32 cvtpk(float a, float b){
    u32 r; asm("v_cvt_pk_bf16_f32 %0, %1, %2" : "=v"(r) : "v"(a), "v"(b)); return r;
}
// packed bf16x2: u32 = bf16(v) | bf16(v - hi)<<16   (used for AT)
__device__ __forceinline__ u32 pack_split(float v){
    u32 h = cvtpk(v, v);
    float hf = __builtin_bit_cast(float, h << 16);
    float r = v - hf;
    u32 l = cvtpk(r, r);
    return __builtin_amdgcn_perm(l, h, 0x05040100u);
}
__device__ __forceinline__ void unpack4(uint4 p, sh4& hi, sh4& lo){
    u32 h0 = __builtin_amdgcn_perm(p.y, p.x, 0x05040100u);
    u32 h1 = __builtin_amdgcn_perm(p.w, p.z, 0x05040100u);
    u32 l0 = __builtin_amdgcn_perm(p.y, p.x, 0x07060302u);
    u32 l1 = __builtin_amdgcn_perm(p.w, p.z, 0x07060302u);
    uint2 h = {h0, h1}, l = {l0, l1};
    hi = __builtin_bit_cast(sh4, h);
    lo = __builtin_bit_cast(sh4, l);
}
__device__ __forceinline__ bf16x8 ldfrag(const short* p){
    sh4 a = *(const sh4*)p;
    sh4 b = *(const sh4*)(p+4);
    return __builtin_shufflevector(a,b,0,1,2,3,4,5,6,7);
}

// ================= prepass: fp32 -> bf16 planes =================
__global__ __launch_bounds__(256) void pack_bf(const float* __restrict__ s, u16* __restrict__ d, int n4){
    int i = blockIdx.x*256 + threadIdx.x;
    if (i >= n4) return;
    float4 v = ((const float4*)s)[i];
    uint2 o = { cvtpk(v.x, v.y), cvtpk(v.z, v.w) };
    ((uint2*)d)[i] = o;
}
__global__ __launch_bounds__(256) void pack_wbf(const float* __restrict__ w0, const float* __restrict__ w1,
                                                const float* __restrict__ w2, const float* __restrict__ w3,
                                                u16* __restrict__ d, int n4){
    const int z = blockIdx.y;
    const float* s = (z==0)?w0:(z==1)?w1:(z==2)?w2:w3;
    int i = blockIdx.x*256 + threadIdx.x;
    if (i >= n4) return;
    float4 v = ((const float4*)s)[i];
    uint2 o = { cvtpk(v.x, v.y), cvtpk(v.z, v.w) };
    ((uint2*)(d + (size_t)z*n4*4))[i] = o;
}

// ================= QKV GEMM: 1-term bf16 x bf16, bf16 out =================
#define GPAD 36

__global__ __launch_bounds__(256,3) void gemm_qkv(const u16* __restrict__ X, const u16* __restrict__ Wb,
        const float* __restrict__ bq, const float* __restrict__ bk, const float* __restrict__ bv,
        u16* __restrict__ oq, u16* __restrict__ okk, u16* __restrict__ ov){
    __shared__ __align__(16) short Ahi[128][GPAD];
    __shared__ __align__(16) short Bhi[128][GPAD];

    const int tid = threadIdx.x;
    const int l = tid & 63, w = tid >> 6;
    const int lq = l & 31, g = l >> 5;
    const int wm = w >> 1, wn = w & 1;
    const int m0 = blockIdx.x * 128;
    const int n0 = blockIdx.y * 128;
    const int z  = blockIdx.z;
    const u16* W = Wb + (size_t)z * D_EMB * D_EMB;
    const float* bias = (z==0) ? bq : (z==1) ? bk : bv;
    u16* out = (z==0) ? oq : (z==1) ? okk : ov;

    f32x16 acc[2][2];
    #pragma unroll
    for (int i=0;i<2;i++)
        #pragma unroll
        for (int j=0;j<2;j++)
            #pragma unroll
            for (int r=0;r<16;r++) acc[i][j][r] = 0.f;

    const int srow = tid >> 1;
    const int skb  = (tid & 1) * 16;
    const u16* ap0 = X + (size_t)(m0+srow)*D_EMB + skb;
    const u16* wp0 = W + (size_t)(n0+srow)*D_EMB + skb;

    uint4 a0 = *(const uint4*)ap0, a1 = *(const uint4*)(ap0+8);
    uint4 w0 = *(const uint4*)wp0, w1 = *(const uint4*)(wp0+8);

    for (int k0 = 0; k0 < D_EMB; k0 += 32) {
        __syncthreads();
        {
            uint2 t;
            t.x=a0.x; t.y=a0.y; *(uint2*)&Ahi[srow][skb]    = t;
            t.x=a0.z; t.y=a0.w; *(uint2*)&Ahi[srow][skb+4]  = t;
            t.x=a1.x; t.y=a1.y; *(uint2*)&Ahi[srow][skb+8]  = t;
            t.x=a1.z; t.y=a1.w; *(uint2*)&Ahi[srow][skb+12] = t;
            t.x=w0.x; t.y=w0.y; *(uint2*)&Bhi[srow][skb]    = t;
            t.x=w0.z; t.y=w0.w; *(uint2*)&Bhi[srow][skb+4]  = t;
            t.x=w1.x; t.y=w1.y; *(uint2*)&Bhi[srow][skb+8]  = t;
            t.x=w1.z; t.y=w1.w; *(uint2*)&Bhi[srow][skb+12] = t;
        }
        if (k0 + 32 < D_EMB){
            const u16* ap = ap0 + k0 + 32;
            const u16* wp = wp0 + k0 + 32;
            a0 = *(const uint4*)ap; a1 = *(const uint4*)(ap+8);
            w0 = *(const uint4*)wp; w1 = *(const uint4*)(wp+8);
        }
        __syncthreads();
        #pragma unroll
        for (int kk=0;kk<2;kk++){
            const int kc = kk*16 + g*8;
            bf16x8 ah[2], bh[2];
            #pragma unroll
            for (int i=0;i<2;i++) ah[i] = ldfrag(&Ahi[wm*64+32*i+lq][kc]);
            #pragma unroll
            for (int j=0;j<2;j++) bh[j] = ldfrag(&Bhi[wn*64+32*j+lq][kc]);
            #pragma unroll
            for (int i=0;i<2;i++)
                #pragma unroll
                for (int j=0;j<2;j++)
                    acc[i][j] = MFMA32(ah[i], bh[j], acc[i][j]);
        }
    }

    #pragma unroll
    for (int j=0;j<2;j++){
        const int c = n0 + wn*64 + 32*j + lq;
        const float bv2 = bias[c];
        #pragma unroll
        for (int i=0;i<2;i++){
            #pragma unroll
            for (int r=0;r<16;r++){
                const int m = m0 + wm*64 + 32*i + (r&3) + 8*(r>>2) + 4*g;
                float v = acc[i][j][r] + bv2;
                if (z==0) v *= SCLQ;
                const int b = m >> 11, n = m & 2047, h = c >> 6, hd = c & 63;
                out[(((size_t)(b*NH + h))*SEQN + n)*HDIM + hd] = (u16)cvtpk(v, v);
            }
        }
    }
}

// ================= out-proj GEMM: A bf16x2 (packed) x W bf16, fp32 out =================
__global__ __launch_bounds__(256,3) void gemm_out(const u32* __restrict__ A, const u16* __restrict__ Wb,
        const float* __restrict__ bo, float* __restrict__ outp){
    __shared__ __align__(16) short Ahi[128][GPAD];
    __shared__ __align__(16) short Alo[128][GPAD];
    __shared__ __align__(16) short Bhi[128][GPAD];

    const int tid = threadIdx.x;
    const int l = tid & 63, w = tid >> 6;
    const int lq = l & 31, g = l >> 5;
    const int wm = w >> 1, wn = w & 1;
    const int m0 = blockIdx.x * 128;
    const int n0 = blockIdx.y * 128;
    const u16* W = Wb + (size_t)3 * D_EMB * D_EMB;

    f32x16 acc[2][2];
    #pragma unroll
    for (int i=0;i<2;i++)
        #pragma unroll
        for (int j=0;j<2;j++)
            #pragma unroll
            for (int r=0;r<16;r++) acc[i][j][r] = 0.f;

    const int srow = tid >> 1;
    const int skb  = (tid & 1) * 16;
    const u32* ap0 = A + (size_t)(m0+srow)*D_EMB + skb;
    const u16* wp0 = W + (size_t)(n0+srow)*D_EMB + skb;

    uint4 areg[4];
    uint4 w0 = *(const uint4*)wp0, w1 = *(const uint4*)(wp0+8);
    #pragma unroll
    for (int c=0;c<4;c++) areg[c] = *(const uint4*)(ap0 + 4*c);

    for (int k0 = 0; k0 < D_EMB; k0 += 32) {
        __syncthreads();
        #pragma unroll
        for (int c=0;c<4;c++){
            sh4 h, lo2; unpack4(areg[c], h, lo2);
            *(sh4*)&Ahi[srow][skb+4*c] = h;
            *(sh4*)&Alo[srow][skb+4*c] = lo2;
        }
        {
            uint2 t;
            t.x=w0.x; t.y=w0.y; *(uint2*)&Bhi[srow][skb]    = t;
            t.x=w0.z; t.y=w0.w; *(uint2*)&Bhi[srow][skb+4]  = t;
            t.x=w1.x; t.y=w1.y; *(uint2*)&Bhi[srow][skb+8]  = t;
            t.x=w1.z; t.y=w1.w; *(uint2*)&Bhi[srow][skb+12] = t;
        }
        if (k0 + 32 < D_EMB){
            const u32* ap = ap0 + k0 + 32;
            const u16* wp = wp0 + k0 + 32;
            #pragma unroll
            for (int c=0;c<4;c++) areg[c] = *(const uint4*)(ap + 4*c);
            w0 = *(const uint4*)wp; w1 = *(const uint4*)(wp+8);
        }
        __syncthreads();
        #pragma unroll
        for (int kk=0;kk<2;kk++){
            const int kc = kk*16 + g*8;
            bf16x8 ah[2], al[2], bh[2];
            #pragma unroll
            for (int i=0;i<2;i++){
                ah[i] = ldfrag(&Ahi[wm*64+32*i+lq][kc]);
                al[i] = ldfrag(&Alo[wm*64+32*i+lq][kc]);
            }
            #pragma unroll
            for (int j=0;j<2;j++) bh[j] = ldfrag(&Bhi[wn*64+32*j+lq][kc]);
            #pragma unroll
            for (int i=0;i<2;i++)
                #pragma unroll
                for (int j=0;j<2;j++){
                    acc[i][j] = MFMA32(ah[i], bh[j], acc[i][j]);
                    acc[i][j] = MFMA32(al[i], bh[j], acc[i][j]);
                }
        }
    }

    #pragma unroll
    for (int j=0;j<2;j++){
        const int c = n0 + wn*64 + 32*j + lq;
        const float bv2 = bo[c];
        #pragma unroll
        for (int i=0;i<2;i++){
            #pragma unroll
            for (int r=0;r<16;r++){
                const int m = m0 + wm*64 + 32*i + (r&3) + 8*(r>>2) + 4*g;
                outp[(size_t)m*D_EMB + c] = acc[i][j][r] + bv2;
            }
        }
    }
}

// ======== flash attention: 4 waves, wave = 64 q-rows x 32-key half, pair-combine ========
// Wave w: q-block (w>>1)*64 (2 groups of 32), key-half (w&1) of each tile.
// K/V frag reads serve 2 q-groups -> reads/MFMA halves vs R12; grid stays 768
// blocks (16 x 48), 4 waves, LDS/barriers/staging identical to R12. Partial
// (O,l) over disjoint key sets combined once at the end via LDS pair-exchange.
#define KB 64
#define KPAD 68
#define NT (SEQN/KB)   // 32

__global__ __launch_bounds__(256,3) void attn_bf(const u16* __restrict__ Qg,
                                                 const u16* __restrict__ Kg,
                                                 const u16* __restrict__ Vg,
                                                 u32* __restrict__ Og) {
    __shared__ __align__(16) short Khi[2][KB][KPAD];
    __shared__ __align__(16) short Vthi[2][HDIM][KPAD];

    const int tid = threadIdx.x;
    const int l = tid & 63, w = tid >> 6;
    const int lq = l & 31, g = l >> 5;
    const int khalf = w & 1;            // this wave's 32-key half
    const int pair  = w >> 1;           // q-block pair id (0 or 1)
    const int qt = blockIdx.x;
    const int bh = blockIdx.y;
    const size_t base = (size_t)bh * SEQN * HDIM;
    const int qrowA = qt*128 + pair*64 + lq;
    const int qrowB = qrowA + 32;

    const int key = tid >> 2, dblk = (tid & 3) * 16;   // K staging: 64 rows x 64 shorts
    const int hd = tid & 63, kg = tid >> 6;            // V^T staging
    const u16* kp0 = Kg + base + (size_t)key*HDIM + dblk;
    const u16* vp0 = Vg + base + (size_t)(kg*16)*HDIM + hd;

    // ---- Q fragments, both groups (bf16, pre-scaled by SCLQ in GEMM) ----
    bf16x8 qhA[4], qhB[4];
    {
        const u16* qpA = Qg + base + (size_t)qrowA*HDIM;
        const u16* qpB = Qg + base + (size_t)qrowB*HDIM;
        #pragma unroll
        for (int kk=0;kk<4;kk++){
            qhA[kk] = __builtin_bit_cast(bf16x8, *(const uint4*)(qpA + kk*16 + g*8));
            qhB[kk] = __builtin_bit_cast(bf16x8, *(const uint4*)(qpB + kk*16 + g*8));
        }
    }

    f32x16 oA0, oA1, oB0, oB1, zro;
    #pragma unroll
    for (int r=0;r<16;r++){ oA0[r]=0.f; oA1[r]=0.f; oB0[r]=0.f; oB1[r]=0.f; zro[r]=0.f; }
    float2 lrA = {0.f, 0.f}, lrB = {0.f, 0.f};

    uint4 kra, krb;
    u32 vt[16];

    auto loadTile = [&](int t){
        const u16* kp = kp0 + (size_t)t*KB*HDIM;
        const u16* vp = vp0 + (size_t)t*KB*HDIM;
        kra = *(const uint4*)kp;
        krb = *(const uint4*)(kp+8);
        #pragma unroll
        for (int i2=0;i2<16;i2++) vt[i2] = vp[(size_t)i2*HDIM];
    };
    auto stageWrite = [&](int cb){
        uint2 t;
        t.x=kra.x; t.y=kra.y; *(uint2*)&Khi[cb][key][dblk]    = t;
        t.x=kra.z; t.y=kra.w; *(uint2*)&Khi[cb][key][dblk+4]  = t;
        t.x=krb.x; t.y=krb.y; *(uint2*)&Khi[cb][key][dblk+8]  = t;
        t.x=krb.z; t.y=krb.w; *(uint2*)&Khi[cb][key][dblk+12] = t;
        #pragma unroll
        for (int c=0;c<4;c++){
            uint2 v2;
            v2.x = __builtin_amdgcn_perm(vt[4*c+1], vt[4*c+0], 0x05040100u);
            v2.y = __builtin_amdgcn_perm(vt[4*c+3], vt[4*c+2], 0x05040100u);
            *(uint2*)&Vthi[cb][hd][kg*16+4*c] = v2;
        }
    };

    loadTile(0);
    stageWrite(0);
    loadTile(1);

    for (int kt=0; kt<NT; kt++){
        const int cb = kt & 1;
        __syncthreads();                       // buf[cb] ready; prev readers drained
        if (kt+1 < NT){
            stageWrite(cb^1);                  // write next tile from prefetched regs
            if (kt+2 < NT) loadTile(kt+2);     // issue loads for tile+2
        }

        // ---- S^T = K_hi . Q^T for this wave's 32-key half, both q-groups ----
        f32x16 sA, sB;
        __builtin_amdgcn_s_setprio(1);
        {
            bf16x8 a = ldfrag(&Khi[cb][khalf*32+lq][g*8]);
            sA = MFMA32(a, qhA[0], zro);
            sB = MFMA32(a, qhB[0], zro);
        }
        #pragma unroll
        for (int kk=1;kk<4;kk++){
            bf16x8 a = ldfrag(&Khi[cb][khalf*32+lq][kk*16 + g*8]);
            sA = MFMA32(a, qhA[kk], sA);
            sB = MFMA32(a, qhB[kk], sB);
        }
        __builtin_amdgcn_s_setprio(0);

        // ---- P = exp2(S), packed row-sums ----
        #pragma unroll
        for (int r=0;r<16;r++){ sA[r] = __builtin_amdgcn_exp2f(sA[r]); sB[r] = __builtin_amdgcn_exp2f(sB[r]); }
        #pragma unroll
        for (int r=0;r<16;r+=2){
            float2 a2 = {sA[r], sA[r+1]};
            float2 b2 = {sB[r], sB[r+1]};
            lrA += a2;
            lrB += b2;
        }

        // ---- pack P (bf16); PV B-frag words via permlane32_swap ----
        u32 pkA[8], pkB[8];
        #pragma unroll
        for (int j=0;j<8;j++){
            pkA[j] = cvtpk(sA[2*j], sA[2*j+1]);
            pkB[j] = cvtpk(sB[2*j], sB[2*j+1]);
        }
        u32 nA0[4], nA1[4], nB0[4], nB1[4];
        #pragma unroll
        for (int a2=0;a2<2;a2++){
            #pragma unroll
            for (int c=0;c<2;c++){
                u32 x0 = pkA[4*a2+c], y0 = pkA[4*a2+2+c];
                asm("v_permlane32_swap_b32 %0, %1" : "+v"(x0), "+v"(y0));
                nA0[2*a2+c] = x0; nA1[2*a2+c] = y0;
                u32 x1 = pkB[4*a2+c], y1 = pkB[4*a2+2+c];
                asm("v_permlane32_swap_b32 %0, %1" : "+v"(x1), "+v"(y1));
                nB0[2*a2+c] = x1; nB1[2*a2+c] = y1;
            }
        }

        // ---- O^T += V^T . P^T over this key-half (V frags shared by both groups) ----
        __builtin_amdgcn_s_setprio(1);
        #pragma unroll
        for (int t2=0; t2<2; t2++){
            const int kk = 2*khalf + t2;       // global k-step
            uint4 wAv = { nA0[2*t2], nA0[2*t2+1], nA1[2*t2], nA1[2*t2+1] };
            uint4 wBv = { nB0[2*t2], nB0[2*t2+1], nB1[2*t2], nB1[2*t2+1] };
            bf16x8 pbA = __builtin_bit_cast(bf16x8, wAv);
            bf16x8 pbB = __builtin_bit_cast(bf16x8, wBv);
            const int kc = kk*16 + g*8;
            bf16x8 v0h = ldfrag(&Vthi[cb][lq][kc]);
            bf16x8 v1h = ldfrag(&Vthi[cb][32+lq][kc]);
            oA0 = MFMA32(v0h, pbA, oA0);
            oA1 = MFMA32(v1h, pbA, oA1);
            oB0 = MFMA32(v0h, pbB, oB0);
            oB1 = MFMA32(v1h, pbB, oB1);
        }
        __builtin_amdgcn_s_setprio(0);
    }

    // ---- pair-combine: odd wave hands its partial (O,l) to even wave via LDS ----
    __syncthreads();                           // all tile reads done; reuse K/V buffers
    {
        float* reg = pair ? (float*)&Vthi[0][0][0] : (float*)&Khi[0][0][0];
        float* slot = reg + (size_t)l*68;      // 64 lanes x 68 floats = 17408 B
        if (khalf){
            #pragma unroll
            for (int r=0;r<16;r++){
                slot[r]    = oA0[r];
                slot[16+r] = oA1[r];
                slot[32+r] = oB0[r];
                slot[48+r] = oB1[r];
            }
            slot[64] = lrA.x + lrA.y;
            slot[65] = lrB.x + lrB.y;
        }
    }
    __syncthreads();
    if (!khalf){
        const float* reg = pair ? (const float*)&Vthi[0][0][0] : (const float*)&Khi[0][0][0];
        const float* slot = reg + (size_t)l*68;
        #pragma unroll
        for (int r=0;r<16;r++){
            oA0[r] += slot[r];
            oA1[r] += slot[16+r];
            oB0[r] += slot[32+r];
            oB1[r] += slot[48+r];
        }
        float lA = lrA.x + lrA.y + slot[64];
        float lB = lrB.x + lrB.y + slot[65];
        lA += __shfl_xor(lA, 32);
        lB += __shfl_xor(lB, 32);

        const int b = bh / NH, h = bh % NH;
        {
            const float inv = 1.f / lA;
            u32* op = Og + ((size_t)(b*SEQN + qrowA))*D_EMB + h*HDIM;
            #pragma unroll
            for (int rq=0; rq<4; rq++){
                uint4 w0, w1;
                w0.x = pack_split(oA0[4*rq+0]*inv); w0.y = pack_split(oA0[4*rq+1]*inv);
                w0.z = pack_split(oA0[4*rq+2]*inv); w0.w = pack_split(oA0[4*rq+3]*inv);
                w1.x = pack_split(oA1[4*rq+0]*inv); w1.y = pack_split(oA1[4*rq+1]*inv);
                w1.z = pack_split(oA1[4*rq+2]*inv); w1.w = pack_split(oA1[4*rq+3]*inv);
                *(uint4*)(op + 8*rq + 4*g)      = w0;
                *(uint4*)(op + 32 + 8*rq + 4*g) = w1;
            }
        }
        {
            const float inv = 1.f / lB;
            u32* op = Og + ((size_t)(b*SEQN + qrowB))*D_EMB + h*HDIM;
            #pragma unroll
            for (int rq=0; rq<4; rq++){
                uint4 w0, w1;
                w0.x = pack_split(oB0[4*rq+0]*inv); w0.y = pack_split(oB0[4*rq+1]*inv);
                w0.z = pack_split(oB0[4*rq+2]*inv); w0.w = pack_split(oB0[4*rq+3]*inv);
                w1.x = pack_split(oB1[4*rq+0]*inv); w1.y = pack_split(oB1[4*rq+1]*inv);
                w1.z = pack_split(oB1[4*rq+2]*inv); w1.w = pack_split(oB1[4*rq+3]*inv);
                *(uint4*)(op + 8*rq + 4*g)      = w0;
                *(uint4*)(op + 32 + 8*rq + 4*g) = w1;
            }
        }
    }
}

// ================= launch =================
extern "C" void kernel_launch(void* const* d_in, const int* in_sizes, int n_in,
                              void* d_out, int out_size, void* d_ws, size_t ws_size,
                              hipStream_t stream) {
    const float* x  = (const float*)d_in[0];
    const float* Wq = (const float*)d_in[1];
    const float* bq = (const float*)d_in[2];
    const float* Wk = (const float*)d_in[3];
    const float* bk = (const float*)d_in[4];
    const float* Wv = (const float*)d_in[5];
    const float* bv = (const float*)d_in[6];
    const float* Wo = (const float*)d_in[7];
    const float* bo = (const float*)d_in[8];

    const size_t per = (size_t)NB*NH*SEQN*HDIM;   // 6,291,456
    const size_t wplane = (size_t)D_EMB*D_EMB;    // 589,824
    u16* base16 = (u16*)d_ws;
    u16* Xbf = base16;
    u16* Qb  = base16 + per;
    u16* Kb  = base16 + 2*per;
    u16* Vb  = base16 + 3*per;
    u16* Wbf = base16 + 4*per;                    // 4 planes
    u32* ATpk = (u32*)(base16 + 4*per + 4*wplane);

    pack_bf<<<dim3((int)(per/4/256)), dim3(256), 0, stream>>>(x, Xbf, (int)(per/4));
    pack_wbf<<<dim3(576,4), dim3(256), 0, stream>>>(Wq, Wk, Wv, Wo, Wbf, (int)(wplane/4));

    gemm_qkv<<<dim3(MTOT/128, D_EMB/128, 3), dim3(256), 0, stream>>>(Xbf, Wbf, bq, bk, bv, Qb, Kb, Vb);

    attn_bf<<<dim3(SEQN/128, NB*NH), dim3(256), 0, stream>>>(Qb, Kb, Vb, ATpk);

    gemm_out<<<dim3(MTOT/128, D_EMB/128), dim3(256), 0, stream>>>(ATpk, Wbf, bo, (float*)d_out);
}

// Round 16
// 142.778 us; speedup vs baseline: 1.1799x; 1.1799x over previous
//
#include <hip/hip_runtime.h>
#include <math.h>

#define D_EMB 768
#define SEQN 2048
#define NB 4
#define NH 12
#define HDIM 64
#define MTOT (NB*SEQN)   // 8192
#define SCLQ 0.18033688011112042f   // 0.125 * log2(e)

typedef unsigned int u32;
typedef unsigned short u16;
typedef short sh4 __attribute__((ext_vector_type(4)));
typedef short bf16x8 __attribute__((ext_vector_type(8)));
typedef float f32x16 __attribute__((ext_vector_type(16)));

#define MFMA32(a,b,c) __builtin_amdgcn_mfma_f32_32x32x16_bf16((a),(b),(c),0,0,0)

__device__ __forceinline__ u32 cvtpk(float a, float b){
    u32 r; asm("v_cvt_pk_bf16_f32 %0, %1, %2" : "=v"(r) : "v"(a), "v"(b)); return r;
}
__device__ __forceinline__ bf16x8 ldfrag(const short* p){
    sh4 a = *(const sh4*)p;
    sh4 b = *(const sh4*)(p+4);
    return __builtin_shufflevector(a,b,0,1,2,3,4,5,6,7);
}

// ================= merged prepass: fp32 -> bf16 (x + 4 W planes, one launch) =================
#define XBLK 6144    // 1,572,864 uint4-groups / 256
#define WBLK 576     // 147,456 / 256

__global__ __launch_bounds__(256) void pack_all(const float* __restrict__ x,
        const float* __restrict__ w0, const float* __restrict__ w1,
        const float* __restrict__ w2, const float* __restrict__ w3,
        u16* __restrict__ dx, u16* __restrict__ dw){
    const int bid = blockIdx.x;
    const float* s; u16* d; int i, n4;
    if (bid < XBLK){
        s = x; d = dx; i = bid*256 + threadIdx.x; n4 = XBLK*256;
    } else {
        const int r = bid - XBLK;
        const int z = r / WBLK, rb = r % WBLK;
        s = (z==0)?w0:(z==1)?w1:(z==2)?w2:w3;
        d = dw + (size_t)z * D_EMB * D_EMB;
        i = rb*256 + threadIdx.x; n4 = WBLK*256;
    }
    if (i >= n4) return;
    float4 v = ((const float4*)s)[i];
    uint2 o = { cvtpk(v.x, v.y), cvtpk(v.z, v.w) };
    ((uint2*)d)[i] = o;
}

// ================= QKV GEMM: 1-term bf16 x bf16, bf16 out =================
#define GPAD 36

__global__ __launch_bounds__(256,3) void gemm_qkv(const u16* __restrict__ X, const u16* __restrict__ Wb,
        const float* __restrict__ bq, const float* __restrict__ bk, const float* __restrict__ bv,
        u16* __restrict__ oq, u16* __restrict__ okk, u16* __restrict__ ov){
    __shared__ __align__(16) short Ahi[128][GPAD];
    __shared__ __align__(16) short Bhi[128][GPAD];

    const int tid = threadIdx.x;
    const int l = tid & 63, w = tid >> 6;
    const int lq = l & 31, g = l >> 5;
    const int wm = w >> 1, wn = w & 1;
    const int m0 = blockIdx.x * 128;
    const int n0 = blockIdx.y * 128;
    const int z  = blockIdx.z;
    const u16* W = Wb + (size_t)z * D_EMB * D_EMB;
    const float* bias = (z==0) ? bq : (z==1) ? bk : bv;
    u16* out = (z==0) ? oq : (z==1) ? okk : ov;

    f32x16 acc[2][2];
    #pragma unroll
    for (int i=0;i<2;i++)
        #pragma unroll
        for (int j=0;j<2;j++)
            #pragma unroll
            for (int r=0;r<16;r++) acc[i][j][r] = 0.f;

    const int srow = tid >> 1;
    const int skb  = (tid & 1) * 16;
    const u16* ap0 = X + (size_t)(m0+srow)*D_EMB + skb;
    const u16* wp0 = W + (size_t)(n0+srow)*D_EMB + skb;

    uint4 a0 = *(const uint4*)ap0, a1 = *(const uint4*)(ap0+8);
    uint4 w0 = *(const uint4*)wp0, w1 = *(const uint4*)(wp0+8);

    for (int k0 = 0; k0 < D_EMB; k0 += 32) {
        __syncthreads();
        {
            uint2 t;
            t.x=a0.x; t.y=a0.y; *(uint2*)&Ahi[srow][skb]    = t;
            t.x=a0.z; t.y=a0.w; *(uint2*)&Ahi[srow][skb+4]  = t;
            t.x=a1.x; t.y=a1.y; *(uint2*)&Ahi[srow][skb+8]  = t;
            t.x=a1.z; t.y=a1.w; *(uint2*)&Ahi[srow][skb+12] = t;
            t.x=w0.x; t.y=w0.y; *(uint2*)&Bhi[srow][skb]    = t;
            t.x=w0.z; t.y=w0.w; *(uint2*)&Bhi[srow][skb+4]  = t;
            t.x=w1.x; t.y=w1.y; *(uint2*)&Bhi[srow][skb+8]  = t;
            t.x=w1.z; t.y=w1.w; *(uint2*)&Bhi[srow][skb+12] = t;
        }
        if (k0 + 32 < D_EMB){
            const u16* ap = ap0 + k0 + 32;
            const u16* wp = wp0 + k0 + 32;
            a0 = *(const uint4*)ap; a1 = *(const uint4*)(ap+8);
            w0 = *(const uint4*)wp; w1 = *(const uint4*)(wp+8);
        }
        __syncthreads();
        #pragma unroll
        for (int kk=0;kk<2;kk++){
            const int kc = kk*16 + g*8;
            bf16x8 ah[2], bh[2];
            #pragma unroll
            for (int i=0;i<2;i++) ah[i] = ldfrag(&Ahi[wm*64+32*i+lq][kc]);
            #pragma unroll
            for (int j=0;j<2;j++) bh[j] = ldfrag(&Bhi[wn*64+32*j+lq][kc]);
            #pragma unroll
            for (int i=0;i<2;i++)
                #pragma unroll
                for (int j=0;j<2;j++)
                    acc[i][j] = MFMA32(ah[i], bh[j], acc[i][j]);
        }
    }

    #pragma unroll
    for (int j=0;j<2;j++){
        const int c = n0 + wn*64 + 32*j + lq;
        const float bv2 = bias[c];
        #pragma unroll
        for (int i=0;i<2;i++){
            #pragma unroll
            for (int r=0;r<16;r++){
                const int m = m0 + wm*64 + 32*i + (r&3) + 8*(r>>2) + 4*g;
                float v = acc[i][j][r] + bv2;
                if (z==0) v *= SCLQ;
                const int b = m >> 11, n = m & 2047, h = c >> 6, hd = c & 63;
                out[(((size_t)(b*NH + h))*SEQN + n)*HDIM + hd] = (u16)cvtpk(v, v);
            }
        }
    }
}

// ================= out-proj GEMM: AT bf16 x W bf16 (1-term), fp32 out =================
__global__ __launch_bounds__(256,3) void gemm_out(const u16* __restrict__ A, const u16* __restrict__ Wb,
        const float* __restrict__ bo, float* __restrict__ outp){
    __shared__ __align__(16) short Ahi[128][GPAD];
    __shared__ __align__(16) short Bhi[128][GPAD];

    const int tid = threadIdx.x;
    const int l = tid & 63, w = tid >> 6;
    const int lq = l & 31, g = l >> 5;
    const int wm = w >> 1, wn = w & 1;
    const int m0 = blockIdx.x * 128;
    const int n0 = blockIdx.y * 128;
    const u16* W = Wb + (size_t)3 * D_EMB * D_EMB;

    f32x16 acc[2][2];
    #pragma unroll
    for (int i=0;i<2;i++)
        #pragma unroll
        for (int j=0;j<2;j++)
            #pragma unroll
            for (int r=0;r<16;r++) acc[i][j][r] = 0.f;

    const int srow = tid >> 1;
    const int skb  = (tid & 1) * 16;
    const u16* ap0 = A + (size_t)(m0+srow)*D_EMB + skb;
    const u16* wp0 = W + (size_t)(n0+srow)*D_EMB + skb;

    uint4 a0 = *(const uint4*)ap0, a1 = *(const uint4*)(ap0+8);
    uint4 w0 = *(const uint4*)wp0, w1 = *(const uint4*)(wp0+8);

    for (int k0 = 0; k0 < D_EMB; k0 += 32) {
        __syncthreads();
        {
            uint2 t;
            t.x=a0.x; t.y=a0.y; *(uint2*)&Ahi[srow][skb]    = t;
            t.x=a0.z; t.y=a0.w; *(uint2*)&Ahi[srow][skb+4]  = t;
            t.x=a1.x; t.y=a1.y; *(uint2*)&Ahi[srow][skb+8]  = t;
            t.x=a1.z; t.y=a1.w; *(uint2*)&Ahi[srow][skb+12] = t;
            t.x=w0.x; t.y=w0.y; *(uint2*)&Bhi[srow][skb]    = t;
            t.x=w0.z; t.y=w0.w; *(uint2*)&Bhi[srow][skb+4]  = t;
            t.x=w1.x; t.y=w1.y; *(uint2*)&Bhi[srow][skb+8]  = t;
            t.x=w1.z; t.y=w1.w; *(uint2*)&Bhi[srow][skb+12] = t;
        }
        if (k0 + 32 < D_EMB){
            const u16* ap = ap0 + k0 + 32;
            const u16* wp = wp0 + k0 + 32;
            a0 = *(const uint4*)ap; a1 = *(const uint4*)(ap+8);
            w0 = *(const uint4*)wp; w1 = *(const uint4*)(wp+8);
        }
        __syncthreads();
        #pragma unroll
        for (int kk=0;kk<2;kk++){
            const int kc = kk*16 + g*8;
            bf16x8 ah[2], bh[2];
            #pragma unroll
            for (int i=0;i<2;i++) ah[i] = ldfrag(&Ahi[wm*64+32*i+lq][kc]);
            #pragma unroll
            for (int j=0;j<2;j++) bh[j] = ldfrag(&Bhi[wn*64+32*j+lq][kc]);
            #pragma unroll
            for (int i=0;i<2;i++)
                #pragma unroll
                for (int j=0;j<2;j++)
                    acc[i][j] = MFMA32(ah[i], bh[j], acc[i][j]);
        }
    }

    #pragma unroll
    for (int j=0;j<2;j++){
        const int c = n0 + wn*64 + 32*j + lq;
        const float bv2 = bo[c];
        #pragma unroll
        for (int i=0;i<2;i++){
            #pragma unroll
            for (int r=0;r<16;r++){
                const int m = m0 + wm*64 + 32*i + (r&3) + 8*(r>>2) + 4*g;
                outp[(size_t)m*D_EMB + c] = acc[i][j][r] + bv2;
            }
        }
    }
}

// ================= flash attention: R12 structure, bf16 AT out =================
// No max-tracking (R10 range argument); permlane32_swap P-exchange (R12).
#define KB 64
#define KPAD 68
#define NT (SEQN/KB)   // 32

__global__ __launch_bounds__(256,3) void attn_bf(const u16* __restrict__ Qg,
                                                 const u16* __restrict__ Kg,
                                                 const u16* __restrict__ Vg,
                                                 u16* __restrict__ Og) {
    __shared__ __align__(16) short Khi[2][KB][KPAD];
    __shared__ __align__(16) short Vthi[2][HDIM][KPAD];

    const int tid = threadIdx.x;
    const int l = tid & 63, w = tid >> 6;
    const int lq = l & 31, g = l >> 5;
    const int qt = blockIdx.x;
    const int bh = blockIdx.y;
    const size_t base = (size_t)bh * SEQN * HDIM;
    const int qrow = qt*128 + w*32 + lq;

    const int key = tid >> 2, dblk = (tid & 3) * 16;   // K: 64 rows x 64 shorts
    const int hd = tid & 63, kg = tid >> 6;            // V^T: row hd, 16 keys per wave
    const u16* kp0 = Kg + base + (size_t)key*HDIM + dblk;
    const u16* vp0 = Vg + base + (size_t)(kg*16)*HDIM + hd;

    // ---- Q fragments (bf16, pre-scaled by SCLQ in GEMM) ----
    bf16x8 qh[4];
    {
        const u16* qp = Qg + base + (size_t)qrow*HDIM;
        #pragma unroll
        for (int kk=0;kk<4;kk++){
            uint4 a = *(const uint4*)(qp + kk*16 + g*8);
            qh[kk] = __builtin_bit_cast(bf16x8, a);
        }
    }

    f32x16 o0, o1, zro;
    #pragma unroll
    for (int r=0;r<16;r++){ o0[r]=0.f; o1[r]=0.f; zro[r]=0.f; }
    float2 lr2 = {0.f, 0.f};

    uint4 kra, krb;
    u32 vt[16];

    auto loadTile = [&](int t){
        const u16* kp = kp0 + (size_t)t*KB*HDIM;
        const u16* vp = vp0 + (size_t)t*KB*HDIM;
        kra = *(const uint4*)kp;
        krb = *(const uint4*)(kp+8);
        #pragma unroll
        for (int i2=0;i2<16;i2++) vt[i2] = vp[(size_t)i2*HDIM];
    };
    auto stageWrite = [&](int cb){
        uint2 t;
        t.x=kra.x; t.y=kra.y; *(uint2*)&Khi[cb][key][dblk]    = t;
        t.x=kra.z; t.y=kra.w; *(uint2*)&Khi[cb][key][dblk+4]  = t;
        t.x=krb.x; t.y=krb.y; *(uint2*)&Khi[cb][key][dblk+8]  = t;
        t.x=krb.z; t.y=krb.w; *(uint2*)&Khi[cb][key][dblk+12] = t;
        #pragma unroll
        for (int c=0;c<4;c++){
            uint2 v2;
            v2.x = __builtin_amdgcn_perm(vt[4*c+1], vt[4*c+0], 0x05040100u);
            v2.y = __builtin_amdgcn_perm(vt[4*c+3], vt[4*c+2], 0x05040100u);
            *(uint2*)&Vthi[cb][hd][kg*16+4*c] = v2;
        }
    };

    loadTile(0);
    stageWrite(0);
    loadTile(1);

    for (int kt=0; kt<NT; kt++){
        const int cb = kt & 1;
        __syncthreads();                       // buf[cb] ready; prev readers drained
        if (kt+1 < NT){
            stageWrite(cb^1);                  // write next tile from prefetched regs
            if (kt+2 < NT) loadTile(kt+2);     // issue loads for tile+2
        }

        // ---- S^T = K_hi . Q_hi^T (log2 domain, bias-free) ----
        f32x16 s0, s1;
        __builtin_amdgcn_s_setprio(1);
        {
            bf16x8 a0h = ldfrag(&Khi[cb][lq][0 + g*8]);
            bf16x8 a1h = ldfrag(&Khi[cb][32+lq][0 + g*8]);
            s0 = MFMA32(a0h, qh[0], zro);
            s1 = MFMA32(a1h, qh[0], zro);
        }
        #pragma unroll
        for (int kk=1;kk<4;kk++){
            const int kc = kk*16 + g*8;
            bf16x8 a0h = ldfrag(&Khi[cb][lq][kc]);
            bf16x8 a1h = ldfrag(&Khi[cb][32+lq][kc]);
            s0 = MFMA32(a0h, qh[kk], s0);
            s1 = MFMA32(a1h, qh[kk], s1);
        }
        __builtin_amdgcn_s_setprio(0);

        // ---- P = exp2(S) directly (no max), packed row-sum trails ----
        #pragma unroll
        for (int r=0;r<16;r++) s0[r] = __builtin_amdgcn_exp2f(s0[r]);
        #pragma unroll
        for (int r=0;r<16;r++) s1[r] = __builtin_amdgcn_exp2f(s1[r]);
        #pragma unroll
        for (int r=0;r<16;r+=2){
            float2 a = {s0[r], s0[r+1]};
            float2 b = {s1[r], s1[r+1]};
            lr2 += a;           // v_pk_add_f32
            lr2 += b;
        }

        // ---- pack P (bf16); build PV B-frag words via permlane32_swap ----
        u32 pk0h[8], pk1h[8];
        #pragma unroll
        for (int j=0;j<8;j++){
            pk0h[j] = cvtpk(s0[2*j], s0[2*j+1]);
            pk1h[j] = cvtpk(s1[2*j], s1[2*j+1]);
        }
        u32 n0[2][4], n1[2][4];
        #pragma unroll
        for (int a2=0;a2<2;a2++){
            #pragma unroll
            for (int c=0;c<2;c++){
                u32 x0 = pk0h[4*a2+c], y0 = pk0h[4*a2+2+c];
                asm("v_permlane32_swap_b32 %0, %1" : "+v"(x0), "+v"(y0));
                n0[0][2*a2+c] = x0; n1[0][2*a2+c] = y0;
                u32 x1 = pk1h[4*a2+c], y1 = pk1h[4*a2+2+c];
                asm("v_permlane32_swap_b32 %0, %1" : "+v"(x1), "+v"(y1));
                n0[1][2*a2+c] = x1; n1[1][2*a2+c] = y1;
            }
        }

        // ---- O^T += V^T . P^T ----
        __builtin_amdgcn_s_setprio(1);
        #pragma unroll
        for (int kk=0;kk<4;kk++){
            const int hblk = kk>>1, a2 = kk&1;
            uint4 whv = { n0[hblk][2*a2], n0[hblk][2*a2+1], n1[hblk][2*a2], n1[hblk][2*a2+1] };
            bf16x8 pbh = __builtin_bit_cast(bf16x8, whv);
            const int kc = kk*16 + g*8;
            bf16x8 v0h = ldfrag(&Vthi[cb][lq][kc]);
            bf16x8 v1h = ldfrag(&Vthi[cb][32+lq][kc]);
            o0 = MFMA32(v0h, pbh, o0);
            o1 = MFMA32(v1h, pbh, o1);
        }
        __builtin_amdgcn_s_setprio(0);
    }

    // ---- epilogue: O^T regs -> bf16 AT (b,n,d) ----
    float l_run = lr2.x + lr2.y;
    l_run += __shfl_xor(l_run, 32);
    const float inv = 1.f / l_run;
    const int b = bh / NH, h = bh % NH;
    u16* op = Og + ((size_t)(b*SEQN + qrow))*D_EMB + h*HDIM;
    #pragma unroll
    for (int rq=0; rq<4; rq++){
        uint2 w0, w1;
        w0.x = cvtpk(o0[4*rq+0]*inv, o0[4*rq+1]*inv);
        w0.y = cvtpk(o0[4*rq+2]*inv, o0[4*rq+3]*inv);
        w1.x = cvtpk(o1[4*rq+0]*inv, o1[4*rq+1]*inv);
        w1.y = cvtpk(o1[4*rq+2]*inv, o1[4*rq+3]*inv);
        *(uint2*)(op + 8*rq + 4*g)      = w0;
        *(uint2*)(op + 32 + 8*rq + 4*g) = w1;
    }
}

// ================= launch =================
extern "C" void kernel_launch(void* const* d_in, const int* in_sizes, int n_in,
                              void* d_out, int out_size, void* d_ws, size_t ws_size,
                              hipStream_t stream) {
    const float* x  = (const float*)d_in[0];
    const float* Wq = (const float*)d_in[1];
    const float* bq = (const float*)d_in[2];
    const float* Wk = (const float*)d_in[3];
    const float* bk = (const float*)d_in[4];
    const float* Wv = (const float*)d_in[5];
    const float* bv = (const float*)d_in[6];
    const float* Wo = (const float*)d_in[7];
    const float* bo = (const float*)d_in[8];

    const size_t per = (size_t)NB*NH*SEQN*HDIM;   // 6,291,456
    const size_t wplane = (size_t)D_EMB*D_EMB;    // 589,824
    u16* base16 = (u16*)d_ws;
    u16* Xbf = base16;
    u16* Qb  = base16 + per;
    u16* Kb  = base16 + 2*per;
    u16* Vb  = base16 + 3*per;
    u16* Wbf = base16 + 4*per;                    // 4 planes
    u16* ATb = base16 + 4*per + 4*wplane;

    pack_all<<<dim3(XBLK + 4*WBLK), dim3(256), 0, stream>>>(x, Wq, Wk, Wv, Wo, Xbf, Wbf);

    gemm_qkv<<<dim3(MTOT/128, D_EMB/128, 3), dim3(256), 0, stream>>>(Xbf, Wbf, bq, bk, bv, Qb, Kb, Vb);

    attn_bf<<<dim3(SEQN/128, NB*NH), dim3(256), 0, stream>>>(Qb, Kb, Vb, ATb);

    gemm_out<<<dim3(MTOT/128, D_EMB/128), dim3(256), 0, stream>>>(ATb, Wbf, bo, (float*)d_out);
}

// Round 17
// 140.649 us; speedup vs baseline: 1.1978x; 1.0151x over previous
//
#include <hip/hip_runtime.h>
#include <math.h>

#define D_EMB 768
#define SEQN 2048
#define NB 4
#define NH 12
#define HDIM 64
#define MTOT (NB*SEQN)   // 8192
#define SCLQ 0.18033688011112042f   // 0.125 * log2(e)

typedef unsigned int u32;
typedef unsigned short u16;
typedef short sh4 __attribute__((ext_vector_type(4)));
typedef short bf16x8 __attribute__((ext_vector_type(8)));
typedef float f32x16 __attribute__((ext_vector_type(16)));

#define MFMA32(a,b,c) __builtin_amdgcn_mfma_f32_32x32x16_bf16((a),(b),(c),0,0,0)

__device__ __forceinline__ u32 cvtpk(float a, float b){
    u32 r; asm("v_cvt_pk_bf16_f32 %0, %1, %2" : "=v"(r) : "v"(a), "v"(b)); return r;
}
__device__ __forceinline__ bf16x8 ldfrag(const short* p){
    sh4 a = *(const sh4*)p;
    sh4 b = *(const sh4*)(p+4);
    return __builtin_shufflevector(a,b,0,1,2,3,4,5,6,7);
}

// ================= merged prepass: fp32 -> bf16 (x + 4 W planes, one launch) =================
#define XBLK 6144    // 1,572,864 uint4-groups / 256
#define WBLK 576     // 147,456 / 256

__global__ __launch_bounds__(256) void pack_all(const float* __restrict__ x,
        const float* __restrict__ w0, const float* __restrict__ w1,
        const float* __restrict__ w2, const float* __restrict__ w3,
        u16* __restrict__ dx, u16* __restrict__ dw){
    const int bid = blockIdx.x;
    const float* s; u16* d; int i, n4;
    if (bid < XBLK){
        s = x; d = dx; i = bid*256 + threadIdx.x; n4 = XBLK*256;
    } else {
        const int r = bid - XBLK;
        const int z = r / WBLK, rb = r % WBLK;
        s = (z==0)?w0:(z==1)?w1:(z==2)?w2:w3;
        d = dw + (size_t)z * D_EMB * D_EMB;
        i = rb*256 + threadIdx.x; n4 = WBLK*256;
    }
    if (i >= n4) return;
    float4 v = ((const float4*)s)[i];
    uint2 o = { cvtpk(v.x, v.y), cvtpk(v.z, v.w) };
    ((uint2*)d)[i] = o;
}

// ================= QKV GEMM: 1-term bf16 x bf16, BK=64, bf16 out =================
#define GPAD 68   // shorts per LDS row at BK=64 (136B stride, 8B-aligned, 2-way banks)

__global__ __launch_bounds__(256,3) void gemm_qkv(const u16* __restrict__ X, const u16* __restrict__ Wb,
        const float* __restrict__ bq, const float* __restrict__ bk, const float* __restrict__ bv,
        u16* __restrict__ oq, u16* __restrict__ okk, u16* __restrict__ ov){
    __shared__ __align__(16) short Ahi[128][GPAD];
    __shared__ __align__(16) short Bhi[128][GPAD];

    const int tid = threadIdx.x;
    const int l = tid & 63, w = tid >> 6;
    const int lq = l & 31, g = l >> 5;
    const int wm = w >> 1, wn = w & 1;
    const int m0 = blockIdx.x * 128;
    const int n0 = blockIdx.y * 128;
    const int z  = blockIdx.z;
    const u16* W = Wb + (size_t)z * D_EMB * D_EMB;
    const float* bias = (z==0) ? bq : (z==1) ? bk : bv;
    u16* out = (z==0) ? oq : (z==1) ? okk : ov;

    f32x16 acc[2][2];
    #pragma unroll
    for (int i=0;i<2;i++)
        #pragma unroll
        for (int j=0;j<2;j++)
            #pragma unroll
            for (int r=0;r<16;r++) acc[i][j][r] = 0.f;

    const int srow = tid >> 1;
    const int skb  = (tid & 1) * 32;   // 32 shorts per thread per row
    const u16* ap0 = X + (size_t)(m0+srow)*D_EMB + skb;
    const u16* wp0 = W + (size_t)(n0+srow)*D_EMB + skb;

    uint4 ar[4], wr[4];
    #pragma unroll
    for (int c=0;c<4;c++){ ar[c] = *(const uint4*)(ap0 + 8*c); wr[c] = *(const uint4*)(wp0 + 8*c); }

    for (int k0 = 0; k0 < D_EMB; k0 += 64) {
        __syncthreads();
        #pragma unroll
        for (int c=0;c<4;c++){
            uint2 t;
            t.x = ar[c].x; t.y = ar[c].y; *(uint2*)&Ahi[srow][skb+8*c]   = t;
            t.x = ar[c].z; t.y = ar[c].w; *(uint2*)&Ahi[srow][skb+8*c+4] = t;
            t.x = wr[c].x; t.y = wr[c].y; *(uint2*)&Bhi[srow][skb+8*c]   = t;
            t.x = wr[c].z; t.y = wr[c].w; *(uint2*)&Bhi[srow][skb+8*c+4] = t;
        }
        if (k0 + 64 < D_EMB){
            const u16* ap = ap0 + k0 + 64;
            const u16* wp = wp0 + k0 + 64;
            #pragma unroll
            for (int c=0;c<4;c++){ ar[c] = *(const uint4*)(ap + 8*c); wr[c] = *(const uint4*)(wp + 8*c); }
        }
        __syncthreads();
        #pragma unroll
        for (int kk=0;kk<4;kk++){
            const int kc = kk*16 + g*8;
            bf16x8 ah[2], bh[2];
            #pragma unroll
            for (int i=0;i<2;i++) ah[i] = ldfrag(&Ahi[wm*64+32*i+lq][kc]);
            #pragma unroll
            for (int j=0;j<2;j++) bh[j] = ldfrag(&Bhi[wn*64+32*j+lq][kc]);
            #pragma unroll
            for (int i=0;i<2;i++)
                #pragma unroll
                for (int j=0;j<2;j++)
                    acc[i][j] = MFMA32(ah[i], bh[j], acc[i][j]);
        }
    }

    #pragma unroll
    for (int j=0;j<2;j++){
        const int c = n0 + wn*64 + 32*j + lq;
        const float bv2 = bias[c];
        #pragma unroll
        for (int i=0;i<2;i++){
            #pragma unroll
            for (int r=0;r<16;r++){
                const int m = m0 + wm*64 + 32*i + (r&3) + 8*(r>>2) + 4*g;
                float v = acc[i][j][r] + bv2;
                if (z==0) v *= SCLQ;
                const int b = m >> 11, n = m & 2047, h = c >> 6, hd = c & 63;
                out[(((size_t)(b*NH + h))*SEQN + n)*HDIM + hd] = (u16)cvtpk(v, v);
            }
        }
    }
}

// ====== out-proj GEMM: AT bf16 x W bf16 (1-term), BK=64, 128x64 tile (grid 768) ======
__global__ __launch_bounds__(256,3) void gemm_out(const u16* __restrict__ A, const u16* __restrict__ Wb,
        const float* __restrict__ bo, float* __restrict__ outp){
    __shared__ __align__(16) short Ahi[128][GPAD];
    __shared__ __align__(16) short Bhi[64][GPAD];

    const int tid = threadIdx.x;
    const int l = tid & 63, w = tid >> 6;
    const int lq = l & 31, g = l >> 5;
    const int wm = w >> 1, wn = w & 1;
    const int m0 = blockIdx.x * 128;
    const int n0 = blockIdx.y * 64;
    const u16* W = Wb + (size_t)3 * D_EMB * D_EMB;

    f32x16 acc[2];
    #pragma unroll
    for (int i=0;i<2;i++)
        #pragma unroll
        for (int r=0;r<16;r++) acc[i][r] = 0.f;

    const int srow = tid >> 1;             // A: 128 rows, 32 shorts/thread
    const int skb  = (tid & 1) * 32;
    const int brow = tid >> 2;             // B: 64 rows, 16 shorts/thread
    const int bkb  = (tid & 3) * 16;
    const u16* ap0 = A + (size_t)(m0+srow)*D_EMB + skb;
    const u16* wp0 = W + (size_t)(n0+brow)*D_EMB + bkb;

    uint4 ar[4], wr[2];
    #pragma unroll
    for (int c=0;c<4;c++) ar[c] = *(const uint4*)(ap0 + 8*c);
    #pragma unroll
    for (int c=0;c<2;c++) wr[c] = *(const uint4*)(wp0 + 8*c);

    for (int k0 = 0; k0 < D_EMB; k0 += 64) {
        __syncthreads();
        #pragma unroll
        for (int c=0;c<4;c++){
            uint2 t;
            t.x = ar[c].x; t.y = ar[c].y; *(uint2*)&Ahi[srow][skb+8*c]   = t;
            t.x = ar[c].z; t.y = ar[c].w; *(uint2*)&Ahi[srow][skb+8*c+4] = t;
        }
        #pragma unroll
        for (int c=0;c<2;c++){
            uint2 t;
            t.x = wr[c].x; t.y = wr[c].y; *(uint2*)&Bhi[brow][bkb+8*c]   = t;
            t.x = wr[c].z; t.y = wr[c].w; *(uint2*)&Bhi[brow][bkb+8*c+4] = t;
        }
        if (k0 + 64 < D_EMB){
            const u16* ap = ap0 + k0 + 64;
            const u16* wp = wp0 + k0 + 64;
            #pragma unroll
            for (int c=0;c<4;c++) ar[c] = *(const uint4*)(ap + 8*c);
            #pragma unroll
            for (int c=0;c<2;c++) wr[c] = *(const uint4*)(wp + 8*c);
        }
        __syncthreads();
        #pragma unroll
        for (int kk=0;kk<4;kk++){
            const int kc = kk*16 + g*8;
            bf16x8 ah[2], bh;
            #pragma unroll
            for (int i=0;i<2;i++) ah[i] = ldfrag(&Ahi[wm*64+32*i+lq][kc]);
            bh = ldfrag(&Bhi[wn*32+lq][kc]);
            #pragma unroll
            for (int i=0;i<2;i++)
                acc[i] = MFMA32(ah[i], bh, acc[i]);
        }
    }

    {
        const int c = n0 + wn*32 + lq;
        const float bv2 = bo[c];
        #pragma unroll
        for (int i=0;i<2;i++){
            #pragma unroll
            for (int r=0;r<16;r++){
                const int m = m0 + wm*64 + 32*i + (r&3) + 8*(r>>2) + 4*g;
                outp[(size_t)m*D_EMB + c] = acc[i][r] + bv2;
            }
        }
    }
}

// ================= flash attention: R12 structure, bf16 AT out =================
// No max-tracking (R10 range argument); permlane32_swap P-exchange (R12).
#define KB 64
#define KPAD 68
#define NT (SEQN/KB)   // 32

__global__ __launch_bounds__(256,3) void attn_bf(const u16* __restrict__ Qg,
                                                 const u16* __restrict__ Kg,
                                                 const u16* __restrict__ Vg,
                                                 u16* __restrict__ Og) {
    __shared__ __align__(16) short Khi[2][KB][KPAD];
    __shared__ __align__(16) short Vthi[2][HDIM][KPAD];

    const int tid = threadIdx.x;
    const int l = tid & 63, w = tid >> 6;
    const int lq = l & 31, g = l >> 5;
    const int qt = blockIdx.x;
    const int bh = blockIdx.y;
    const size_t base = (size_t)bh * SEQN * HDIM;
    const int qrow = qt*128 + w*32 + lq;

    const int key = tid >> 2, dblk = (tid & 3) * 16;   // K: 64 rows x 64 shorts
    const int hd = tid & 63, kg = tid >> 6;            // V^T: row hd, 16 keys per wave
    const u16* kp0 = Kg + base + (size_t)key*HDIM + dblk;
    const u16* vp0 = Vg + base + (size_t)(kg*16)*HDIM + hd;

    // ---- Q fragments (bf16, pre-scaled by SCLQ in GEMM) ----
    bf16x8 qh[4];
    {
        const u16* qp = Qg + base + (size_t)qrow*HDIM;
        #pragma unroll
        for (int kk=0;kk<4;kk++){
            uint4 a = *(const uint4*)(qp + kk*16 + g*8);
            qh[kk] = __builtin_bit_cast(bf16x8, a);
        }
    }

    f32x16 o0, o1, zro;
    #pragma unroll
    for (int r=0;r<16;r++){ o0[r]=0.f; o1[r]=0.f; zro[r]=0.f; }
    float2 lr2 = {0.f, 0.f};

    uint4 kra, krb;
    u32 vt[16];

    auto loadTile = [&](int t){
        const u16* kp = kp0 + (size_t)t*KB*HDIM;
        const u16* vp = vp0 + (size_t)t*KB*HDIM;
        kra = *(const uint4*)kp;
        krb = *(const uint4*)(kp+8);
        #pragma unroll
        for (int i2=0;i2<16;i2++) vt[i2] = vp[(size_t)i2*HDIM];
    };
    auto stageWrite = [&](int cb){
        uint2 t;
        t.x=kra.x; t.y=kra.y; *(uint2*)&Khi[cb][key][dblk]    = t;
        t.x=kra.z; t.y=kra.w; *(uint2*)&Khi[cb][key][dblk+4]  = t;
        t.x=krb.x; t.y=krb.y; *(uint2*)&Khi[cb][key][dblk+8]  = t;
        t.x=krb.z; t.y=krb.w; *(uint2*)&Khi[cb][key][dblk+12] = t;
        #pragma unroll
        for (int c=0;c<4;c++){
            uint2 v2;
            v2.x = __builtin_amdgcn_perm(vt[4*c+1], vt[4*c+0], 0x05040100u);
            v2.y = __builtin_amdgcn_perm(vt[4*c+3], vt[4*c+2], 0x05040100u);
            *(uint2*)&Vthi[cb][hd][kg*16+4*c] = v2;
        }
    };

    loadTile(0);
    stageWrite(0);
    loadTile(1);

    for (int kt=0; kt<NT; kt++){
        const int cb = kt & 1;
        __syncthreads();                       // buf[cb] ready; prev readers drained
        if (kt+1 < NT){
            stageWrite(cb^1);                  // write next tile from prefetched regs
            if (kt+2 < NT) loadTile(kt+2);     // issue loads for tile+2
        }

        // ---- S^T = K_hi . Q_hi^T (log2 domain, bias-free) ----
        f32x16 s0, s1;
        __builtin_amdgcn_s_setprio(1);
        {
            bf16x8 a0h = ldfrag(&Khi[cb][lq][0 + g*8]);
            bf16x8 a1h = ldfrag(&Khi[cb][32+lq][0 + g*8]);
            s0 = MFMA32(a0h, qh[0], zro);
            s1 = MFMA32(a1h, qh[0], zro);
        }
        #pragma unroll
        for (int kk=1;kk<4;kk++){
            const int kc = kk*16 + g*8;
            bf16x8 a0h = ldfrag(&Khi[cb][lq][kc]);
            bf16x8 a1h = ldfrag(&Khi[cb][32+lq][kc]);
            s0 = MFMA32(a0h, qh[kk], s0);
            s1 = MFMA32(a1h, qh[kk], s1);
        }
        __builtin_amdgcn_s_setprio(0);

        // ---- P = exp2(S) directly (no max), packed row-sum trails ----
        #pragma unroll
        for (int r=0;r<16;r++) s0[r] = __builtin_amdgcn_exp2f(s0[r]);
        #pragma unroll
        for (int r=0;r<16;r++) s1[r] = __builtin_amdgcn_exp2f(s1[r]);
        #pragma unroll
        for (int r=0;r<16;r+=2){
            float2 a = {s0[r], s0[r+1]};
            float2 b = {s1[r], s1[r+1]};
            lr2 += a;           // v_pk_add_f32
            lr2 += b;
        }

        // ---- pack P (bf16); build PV B-frag words via permlane32_swap ----
        u32 pk0h[8], pk1h[8];
        #pragma unroll
        for (int j=0;j<8;j++){
            pk0h[j] = cvtpk(s0[2*j], s0[2*j+1]);
            pk1h[j] = cvtpk(s1[2*j], s1[2*j+1]);
        }
        u32 n0[2][4], n1[2][4];
        #pragma unroll
        for (int a2=0;a2<2;a2++){
            #pragma unroll
            for (int c=0;c<2;c++){
                u32 x0 = pk0h[4*a2+c], y0 = pk0h[4*a2+2+c];
                asm("v_permlane32_swap_b32 %0, %1" : "+v"(x0), "+v"(y0));
                n0[0][2*a2+c] = x0; n1[0][2*a2+c] = y0;
                u32 x1 = pk1h[4*a2+c], y1 = pk1h[4*a2+2+c];
                asm("v_permlane32_swap_b32 %0, %1" : "+v"(x1), "+v"(y1));
                n0[1][2*a2+c] = x1; n1[1][2*a2+c] = y1;
            }
        }

        // ---- O^T += V^T . P^T ----
        __builtin_amdgcn_s_setprio(1);
        #pragma unroll
        for (int kk=0;kk<4;kk++){
            const int hblk = kk>>1, a2 = kk&1;
            uint4 whv = { n0[hblk][2*a2], n0[hblk][2*a2+1], n1[hblk][2*a2], n1[hblk][2*a2+1] };
            bf16x8 pbh = __builtin_bit_cast(bf16x8, whv);
            const int kc = kk*16 + g*8;
            bf16x8 v0h = ldfrag(&Vthi[cb][lq][kc]);
            bf16x8 v1h = ldfrag(&Vthi[cb][32+lq][kc]);
            o0 = MFMA32(v0h, pbh, o0);
            o1 = MFMA32(v1h, pbh, o1);
        }
        __builtin_amdgcn_s_setprio(0);
    }

    // ---- epilogue: O^T regs -> bf16 AT (b,n,d) ----
    float l_run = lr2.x + lr2.y;
    l_run += __shfl_xor(l_run, 32);
    const float inv = 1.f / l_run;
    const int b = bh / NH, h = bh % NH;
    u16* op = Og + ((size_t)(b*SEQN + qrow))*D_EMB + h*HDIM;
    #pragma unroll
    for (int rq=0; rq<4; rq++){
        uint2 w0, w1;
        w0.x = cvtpk(o0[4*rq+0]*inv, o0[4*rq+1]*inv);
        w0.y = cvtpk(o0[4*rq+2]*inv, o0[4*rq+3]*inv);
        w1.x = cvtpk(o1[4*rq+0]*inv, o1[4*rq+1]*inv);
        w1.y = cvtpk(o1[4*rq+2]*inv, o1[4*rq+3]*inv);
        *(uint2*)(op + 8*rq + 4*g)      = w0;
        *(uint2*)(op + 32 + 8*rq + 4*g) = w1;
    }
}

// ================= launch =================
extern "C" void kernel_launch(void* const* d_in, const int* in_sizes, int n_in,
                              void* d_out, int out_size, void* d_ws, size_t ws_size,
                              hipStream_t stream) {
    const float* x  = (const float*)d_in[0];
    const float* Wq = (const float*)d_in[1];
    const float* bq = (const float*)d_in[2];
    const float* Wk = (const float*)d_in[3];
    const float* bk = (const float*)d_in[4];
    const float* Wv = (const float*)d_in[5];
    const float* bv = (const float*)d_in[6];
    const float* Wo = (const float*)d_in[7];
    const float* bo = (const float*)d_in[8];

    const size_t per = (size_t)NB*NH*SEQN*HDIM;   // 6,291,456
    const size_t wplane = (size_t)D_EMB*D_EMB;    // 589,824
    u16* base16 = (u16*)d_ws;
    u16* Xbf = base16;
    u16* Qb  = base16 + per;
    u16* Kb  = base16 + 2*per;
    u16* Vb  = base16 + 3*per;
    u16* Wbf = base16 + 4*per;                    // 4 planes
    u16* ATb = base16 + 4*per + 4*wplane;

    pack_all<<<dim3(XBLK + 4*WBLK), dim3(256), 0, stream>>>(x, Wq, Wk, Wv, Wo, Xbf, Wbf);

    gemm_qkv<<<dim3(MTOT/128, D_EMB/128, 3), dim3(256), 0, stream>>>(Xbf, Wbf, bq, bk, bv, Qb, Kb, Vb);

    attn_bf<<<dim3(SEQN/128, NB*NH), dim3(256), 0, stream>>>(Qb, Kb, Vb, ATb);

    gemm_out<<<dim3(MTOT/128, D_EMB/64), dim3(256), 0, stream>>>(ATb, Wbf, bo, (float*)d_out);
}